// Round 6
// baseline (381.830 us; speedup 1.0000x reference)
//
#include <hip/hip_runtime.h>
#include <hip/hip_bf16.h>
#include <math.h>

#define NB 16384
#define NF 32
#define ND 64
#define NIN 2048

typedef __attribute__((ext_vector_type(8))) short fragA;   // 8 bf16
typedef __attribute__((ext_vector_type(4))) float fragC;   // 4 fp32

#define MFMA(a, b, c) __builtin_amdgcn_mfma_f32_16x16x32_bf16((a), (b), (c), 0, 0, 0)

__device__ __forceinline__ short f2bf(float f) {
    union { float f; unsigned u; } v; v.f = f;
    return (short)((v.u + 0x7fffu + ((v.u >> 16) & 1u)) >> 16);  // RNE
}
// 8 consecutive fp32 -> bf16 fragment via packed cvt (v_cvt_pk_bf16_f32)
__device__ __forceinline__ fragA cvt8(const float* p) {
    const float4 a = *(const float4*)p;
    const float4 b = *(const float4*)(p + 4);
    union { __hip_bfloat162 h[4]; fragA f; } u;
    u.h[0] = __float22bfloat162_rn(make_float2(a.x, a.y));
    u.h[1] = __float22bfloat162_rn(make_float2(a.z, a.w));
    u.h[2] = __float22bfloat162_rn(make_float2(b.x, b.y));
    u.h[3] = __float22bfloat162_rn(make_float2(b.z, b.w));
    return u.f;
}
// fast elu / gated-linear using hardware exp/rcp paths
__device__ __forceinline__ float fast_elu(float v) {
    return v > 0.f ? v : (__expf(v) - 1.f);
}
__device__ __forceinline__ float fast_gate(float ll, float gg) {
    return __fdividef(ll, 1.f + __expf(-gg));
}

// ---------------------------------------------------------------------------
// Prologue: weights -> bf16 B-fragment-linear layout in d_ws (unchanged).
// ---------------------------------------------------------------------------
__global__ __launch_bounds__(256) void prep_kernel(
    const float* __restrict__ w1, const float* __restrict__ w2,
    const float* __restrict__ gw, const float* __restrict__ lw,
    const float* __restrict__ mw1, const float* __restrict__ mlw,
    const float* __restrict__ mw2, const float* __restrict__ mgw,
    const float* __restrict__ mlw2,
    short* __restrict__ wsout)
{
    int F = blockIdx.x * 256 + threadIdx.x;
    fragA o;
    if (F < 65536) {
        int mat = F >> 14;
        int f   = (F >> 9) & 31;
        int nt  = (F >> 7) & 3;
        int s   = (F >> 6) & 1;
        int l   = F & 63;
        const float* src = (mat == 0 ? w1 : mat == 1 ? w2 : mat == 2 ? gw : lw)
                           + (size_t)f * 4096;
        int n  = nt * 16 + (l & 15);
        int k0 = s * 32 + ((l >> 4) << 3);
#pragma unroll
        for (int j = 0; j < 8; ++j) o[j] = f2bf(src[(k0 + j) * 64 + n]);
    } else if (F < 90112) {
        int G  = F - 65536;
        int f  = G / 768;
        int r  = G - f * 768;
        int nt = r >> 7;
        int s  = (r >> 6) & 1;
        int l  = r & 63;
        int n  = nt * 16 + (l & 15);
        int k0 = f * 64 + s * 32 + ((l >> 4) << 3);
        if (n < 64) {
#pragma unroll
            for (int j = 0; j < 8; ++j) o[j] = f2bf(mw1[(size_t)(k0 + j) * 64 + n]);
        } else {
#pragma unroll
            for (int j = 0; j < 8; ++j) o[j] = f2bf(mlw[(size_t)(k0 + j) * 32 + (n - 64)]);
        }
    } else {
        int G2 = F - 90112;
        if (G2 < 256) {
            int nt = G2 >> 7, s = (G2 >> 6) & 1, l = G2 & 63;
            int n = nt * 16 + (l & 15);
            int k0 = s * 32 + ((l >> 4) << 3);
#pragma unroll
            for (int j = 0; j < 8; ++j) o[j] = f2bf(mw2[(k0 + j) * 32 + n]);
        } else {
            int G3 = G2 - 256;
            const float* src = (G3 < 128) ? mgw : mlw2;
            G3 &= 127;
            int nt = G3 >> 6, l = G3 & 63;
            int n = nt * 16 + (l & 15);
            int k0 = (l >> 4) << 3;
#pragma unroll
            for (int j = 0; j < 8; ++j) o[j] = f2bf(src[(k0 + j) * 32 + n]);
        }
    }
    ((fragA*)wsout)[F] = o;
}

// ---------------------------------------------------------------------------
// Fused kernel.  16 rows/block, 4 waves.  Phase 1: waves split f (8 each).
// Phase 2: each wave runs TWO concurrent GRN chains (fi, fi+4) for ILP.
// LDS map (floats, total 9216 = 36,864 B -> 4 blocks/CU):
//   phase 1 (all inside [0,8704)):
//     redS [0,1552) atomic partials; gS [0,640) lS [768,1408) (alias, later)
//     hS1 [1552,2640); resS [2640,3216); h2S [3216,3792)
//   phase 2:
//     hW   [0,8704)    = 4 waves x 2 chains x 16x68
//     outS [0,4096)    aliases hW after the end-of-loop barrier
//   maskS  [8704,9216) persists phase 1 -> phase 2
// ---------------------------------------------------------------------------
__global__ __launch_bounds__(256, 4) void fused_kernel(
    const float* __restrict__ x,
    const short* __restrict__ wfrag, const short* __restrict__ mwfrag,
    const short* __restrict__ swfrag,
    const float* __restrict__ mb1, const float* __restrict__ mb2,
    const float* __restrict__ mlb, const float* __restrict__ mgb,
    const float* __restrict__ mlb2,
    const float* __restrict__ mgamma, const float* __restrict__ mbeta,
    const float* __restrict__ b1, const float* __restrict__ b2,
    const float* __restrict__ gb, const float* __restrict__ lb,
    const float* __restrict__ gamma, const float* __restrict__ beta,
    float* __restrict__ mask_out, float* __restrict__ out)
{
    __shared__ float smem[9216];
    float* redS  = smem;
    float* gS    = smem;
    float* lS    = smem + 768;
    float* hS1   = smem + 1552;
    float* resS  = smem + 2640;
    float* h2S   = smem + 3216;
    float* outS  = smem;
    float* maskS = smem + 8704;

    const int tid = threadIdx.x;
    const int w = tid >> 6, l = tid & 63;
    const int row0 = blockIdx.x * 16;
    const int m = l & 15, q = l >> 4;

    const fragA* wf  = (const fragA*)wfrag;
    const fragA* mwf = (const fragA*)mwfrag;
    const fragA* swf = (const fragA*)swfrag;

    // zero the shared mask-partial accumulator
    for (int i = tid; i < 1552; i += 256) redS[i] = 0.f;
    __syncthreads();

    // ------------------------- Phase 1: mask -------------------------
    fragC acc[6];
#pragma unroll
    for (int nt = 0; nt < 6; ++nt) acc[nt] = (fragC){0.f, 0.f, 0.f, 0.f};

    const float* xpm = x + (size_t)(row0 + m) * NIN + q * 8;
    for (int fi = 0; fi < 8; ++fi) {
        int f = w * 8 + fi;
        const float* xp = xpm + f * ND;
        fragA a0 = cvt8(xp), a1 = cvt8(xp + 32);
        const size_t fb = (size_t)f * 768 + l;
#pragma unroll
        for (int nt = 0; nt < 6; ++nt) {
            acc[nt] = MFMA(a0, mwf[fb + nt * 128], acc[nt]);
            acc[nt] = MFMA(a1, mwf[fb + nt * 128 + 64], acc[nt]);
        }
    }
#pragma unroll
    for (int nt = 0; nt < 6; ++nt)
#pragma unroll
        for (int rg = 0; rg < 4; ++rg)
            atomicAdd(&redS[(q * 4 + rg) * 97 + nt * 16 + m], acc[nt][rg]);
    __syncthreads();

    // stage A: h = elu(.+mb1) -> hS1 ; res = .+mlb -> resS
    {
        int r = tid & 15, cb = tid >> 4;
#pragma unroll
        for (int i = 0; i < 6; ++i) {
            int c = cb + i * 16;
            float s = redS[r * 97 + c];
            if (c < 64) {
                hS1[r * 68 + c] = fast_elu(s + mb1[c]);
            } else {
                resS[r * 36 + (c - 64)] = s + mlb[c - 64];
            }
        }
    }
    __syncthreads();

    // stage B (MFMA, waves 0-1): h2 = h @ mw2 + mb2 -> h2S
    if (w < 2) {
        const float* ap = hS1 + m * 68 + q * 8;
        fragA a0 = cvt8(ap), a1 = cvt8(ap + 32);
        fragC c = {0.f, 0.f, 0.f, 0.f};
        c = MFMA(a0, swf[w * 128 + l], c);
        c = MFMA(a1, swf[w * 128 + 64 + l], c);
        float bv = mb2[w * 16 + m];
#pragma unroll
        for (int rg = 0; rg < 4; ++rg)
            h2S[(q * 4 + rg) * 36 + w * 16 + m] = c[rg] + bv;
    }
    __syncthreads();

    // stage C (MFMA, all waves): gate (waves 0-1) / lin (waves 2-3)
    {
        int ntc = w & 1;
        int isl = w >> 1;
        fragA a = cvt8(h2S + m * 36 + q * 8);          // K=32
        fragC c = {0.f, 0.f, 0.f, 0.f};
        c = MFMA(a, swf[256 + isl * 128 + ntc * 64 + l], c);
        float* dst = isl ? lS : gS;
#pragma unroll
        for (int rg = 0; rg < 4; ++rg)
            dst[(q * 4 + rg) * 36 + ntc * 16 + m] = c[rg];
    }
    __syncthreads();

    // stage D: pre = sigmoid(g+mgb)*(l+mlb2)+res ; LN(F=32)+softmax (wave 0)
    if (w == 0) {
        int r2 = l >> 2, c0 = (l & 3) * 8;
        float pre[8];
#pragma unroll
        for (int i = 0; i < 8; ++i) {
            int c = c0 + i;
            float gg = gS[r2 * 36 + c] + mgb[c];
            float ll = lS[r2 * 36 + c] + mlb2[c];
            pre[i] = fast_gate(ll, gg) + resS[r2 * 36 + c];
        }
        float s1 = 0.f;
#pragma unroll
        for (int i = 0; i < 8; ++i) s1 += pre[i];
        s1 += __shfl_xor(s1, 1); s1 += __shfl_xor(s1, 2);
        float mean = s1 * (1.f / 32.f);
        float s2 = 0.f;
#pragma unroll
        for (int i = 0; i < 8; ++i) { float d = pre[i] - mean; s2 += d * d; }
        s2 += __shfl_xor(s2, 1); s2 += __shfl_xor(s2, 2);
        float inv = rsqrtf(s2 * (1.f / 32.f) + 1e-5f);
        float ln[8]; float mx = -3.4e38f;
#pragma unroll
        for (int i = 0; i < 8; ++i) {
            ln[i] = (pre[i] - mean) * inv * mgamma[c0 + i] + mbeta[c0 + i];
            mx = fmaxf(mx, ln[i]);
        }
        mx = fmaxf(mx, __shfl_xor(mx, 1));
        mx = fmaxf(mx, __shfl_xor(mx, 2));
        float ssum = 0.f;
#pragma unroll
        for (int i = 0; i < 8; ++i) { ln[i] = __expf(ln[i] - mx); ssum += ln[i]; }
        ssum += __shfl_xor(ssum, 1); ssum += __shfl_xor(ssum, 2);
        float rs = __fdividef(1.f, ssum);
        float* mo = mask_out + (size_t)(row0 + r2) * 32 + c0;
        *(float4*)mo       = (float4){ln[0] * rs, ln[1] * rs, ln[2] * rs, ln[3] * rs};
        *(float4*)(mo + 4) = (float4){ln[4] * rs, ln[5] * rs, ln[6] * rs, ln[7] * rs};
#pragma unroll
        for (int i = 0; i < 8; ++i) maskS[r2 * 32 + c0 + i] = ln[i] * rs;
    }
    __syncthreads();

    // ---------------- Phase 2: GRNs, 2 concurrent chains ----------------
    float* hWa = smem + w * 2176;          // chain A h buffer (16x68)
    float* hWb = smem + w * 2176 + 1088;   // chain B h buffer

    fragC oac[4];
#pragma unroll
    for (int nt = 0; nt < 4; ++nt) oac[nt] = (fragC){0.f, 0.f, 0.f, 0.f};

    for (int fi = 0; fi < 4; ++fi) {
        const int fA = w * 8 + fi;
        const int fB = fA + 4;

        // GEMM1 both chains: h1 = elu(x @ w1 + b1)
        {
            const float* xpA = xpm + fA * ND;
            const float* xpB = xpm + fB * ND;
            fragA a0A = cvt8(xpA), a1A = cvt8(xpA + 32);
            fragA a0B = cvt8(xpB), a1B = cvt8(xpB + 32);
            const size_t bA = (size_t)fA * 512 + l;
            const size_t bB = (size_t)fB * 512 + l;
#pragma unroll
            for (int nt = 0; nt < 4; ++nt) {
                fragC cA = {0.f, 0.f, 0.f, 0.f}, cB = {0.f, 0.f, 0.f, 0.f};
                cA = MFMA(a0A, wf[bA + nt * 128], cA);
                cB = MFMA(a0B, wf[bB + nt * 128], cB);
                cA = MFMA(a1A, wf[bA + nt * 128 + 64], cA);
                cB = MFMA(a1B, wf[bB + nt * 128 + 64], cB);
                int col = nt * 16 + m;
                float bvA = b1[fA * 64 + col], bvB = b1[fB * 64 + col];
#pragma unroll
                for (int rg = 0; rg < 4; ++rg) {
                    hWa[(q * 4 + rg) * 68 + col] = fast_elu(cA[rg] + bvA);
                    hWb[(q * 4 + rg) * 68 + col] = fast_elu(cB[rg] + bvB);
                }
            }
        }
        // GEMM2 both chains: h2 = h1 @ w2 + b2 (read frags fully, then write)
        {
            const float* apA = hWa + m * 68 + q * 8;
            const float* apB = hWb + m * 68 + q * 8;
            fragA a0A = cvt8(apA), a1A = cvt8(apA + 32);
            fragA a0B = cvt8(apB), a1B = cvt8(apB + 32);
            const size_t bA = ((size_t)(NF + fA)) * 512 + l;
            const size_t bB = ((size_t)(NF + fB)) * 512 + l;
            fragC ccA[4], ccB[4];
#pragma unroll
            for (int nt = 0; nt < 4; ++nt) {
                fragC cA = {0.f, 0.f, 0.f, 0.f}, cB = {0.f, 0.f, 0.f, 0.f};
                cA = MFMA(a0A, wf[bA + nt * 128], cA);
                cB = MFMA(a0B, wf[bB + nt * 128], cB);
                cA = MFMA(a1A, wf[bA + nt * 128 + 64], cA);
                cB = MFMA(a1B, wf[bB + nt * 128 + 64], cB);
                ccA[nt] = cA; ccB[nt] = cB;
            }
#pragma unroll
            for (int nt = 0; nt < 4; ++nt) {
                int col = nt * 16 + m;
                float bvA = b2[fA * 64 + col], bvB = b2[fB * 64 + col];
#pragma unroll
                for (int rg = 0; rg < 4; ++rg) {
                    hWa[(q * 4 + rg) * 68 + col] = ccA[nt][rg] + bvA;
                    hWb[(q * 4 + rg) * 68 + col] = ccB[nt][rg] + bvB;
                }
            }
        }
        // GEMM3+4 both chains, then epilogues
        {
            const float* apA = hWa + m * 68 + q * 8;
            const float* apB = hWb + m * 68 + q * 8;
            fragA a0A = cvt8(apA), a1A = cvt8(apA + 32);
            fragA a0B = cvt8(apB), a1B = cvt8(apB + 32);
            const size_t bgA = ((size_t)(2 * NF + fA)) * 512 + l;
            const size_t blA = ((size_t)(3 * NF + fA)) * 512 + l;
            const size_t bgB = ((size_t)(2 * NF + fB)) * 512 + l;
            const size_t blB = ((size_t)(3 * NF + fB)) * 512 + l;
            fragC gaA[4], laA[4], gaB[4], laB[4];
#pragma unroll
            for (int nt = 0; nt < 4; ++nt) {
                fragC g = {0.f, 0.f, 0.f, 0.f}, li = {0.f, 0.f, 0.f, 0.f};
                g  = MFMA(a0A, wf[bgA + nt * 128], g);
                g  = MFMA(a1A, wf[bgA + nt * 128 + 64], g);
                li = MFMA(a0A, wf[blA + nt * 128], li);
                li = MFMA(a1A, wf[blA + nt * 128 + 64], li);
                gaA[nt] = g; laA[nt] = li;
            }
#pragma unroll
            for (int nt = 0; nt < 4; ++nt) {
                fragC g = {0.f, 0.f, 0.f, 0.f}, li = {0.f, 0.f, 0.f, 0.f};
                g  = MFMA(a0B, wf[bgB + nt * 128], g);
                g  = MFMA(a1B, wf[bgB + nt * 128 + 64], g);
                li = MFMA(a0B, wf[blB + nt * 128], li);
                li = MFMA(a1B, wf[blB + nt * 128 + 64], li);
                gaB[nt] = g; laB[nt] = li;
            }
            // epilogue chain A then chain B
#pragma unroll
            for (int ch = 0; ch < 2; ++ch) {
                const int f = ch ? fB : fA;
                fragC* ga = ch ? gaB : gaA;
                fragC* la = ch ? laB : laA;
                float gbv[4], lbv[4], gmv[4], btv[4];
#pragma unroll
                for (int nt = 0; nt < 4; ++nt) {
                    int c = f * 64 + nt * 16 + m;
                    gbv[nt] = gb[c]; lbv[nt] = lb[c];
                    gmv[nt] = gamma[c]; btv[nt] = beta[c];
                }
#pragma unroll
                for (int rg = 0; rg < 4; ++rg) {
                    int row = q * 4 + rg;
                    float mk = maskS[row * 32 + f];
                    float val[4];
#pragma unroll
                    for (int nt = 0; nt < 4; ++nt) {
                        float gg = ga[nt][rg] + gbv[nt];
                        float ll = la[nt][rg] + lbv[nt];
                        float resid = x[(size_t)(row0 + row) * NIN + f * ND + nt * 16 + m];
                        val[nt] = fast_gate(ll, gg) + resid;
                    }
                    float s1 = val[0] + val[1] + val[2] + val[3];
                    s1 += __shfl_xor(s1, 1); s1 += __shfl_xor(s1, 2);
                    s1 += __shfl_xor(s1, 4); s1 += __shfl_xor(s1, 8);
                    float mean = s1 * (1.f / 64.f);
                    float s2 = 0.f;
#pragma unroll
                    for (int nt = 0; nt < 4; ++nt) { float d = val[nt] - mean; s2 += d * d; }
                    s2 += __shfl_xor(s2, 1); s2 += __shfl_xor(s2, 2);
                    s2 += __shfl_xor(s2, 4); s2 += __shfl_xor(s2, 8);
                    float inv = rsqrtf(s2 * (1.f / 64.f) + 1e-5f);
#pragma unroll
                    for (int nt = 0; nt < 4; ++nt) {
                        float vec = (val[nt] - mean) * inv * gmv[nt] + btv[nt];
                        oac[nt][rg] += mk * vec;
                    }
                }
            }
        }
    }

    // cross-wave output reduction (outS aliases hW -> barrier first)
    __syncthreads();
#pragma unroll
    for (int nt = 0; nt < 4; ++nt)
#pragma unroll
        for (int rg = 0; rg < 4; ++rg)
            outS[w * 1024 + (q * 4 + rg) * 64 + nt * 16 + m] = oac[nt][rg];
    __syncthreads();
    {
        int t4 = tid * 4;
        int r = t4 >> 6, c = t4 & 63;
        float v[4];
#pragma unroll
        for (int j = 0; j < 4; ++j) {
            v[j] = outS[r * 64 + c + j] + outS[1024 + r * 64 + c + j]
                 + outS[2048 + r * 64 + c + j] + outS[3072 + r * 64 + c + j];
        }
        *(float4*)(out + (size_t)(row0 + r) * 64 + c) = (float4){v[0], v[1], v[2], v[3]};
    }
}

// ---------------------------------------------------------------------------
extern "C" void kernel_launch(void* const* d_in, const int* in_sizes, int n_in,
                              void* d_out, int out_size, void* d_ws, size_t ws_size,
                              hipStream_t stream) {
    const float* x      = (const float*)d_in[0];
    const float* mw1    = (const float*)d_in[1];
    const float* mb1    = (const float*)d_in[2];
    const float* mw2    = (const float*)d_in[3];
    const float* mb2    = (const float*)d_in[4];
    const float* mlw    = (const float*)d_in[5];
    const float* mlb    = (const float*)d_in[6];
    const float* mgw    = (const float*)d_in[7];
    const float* mgb    = (const float*)d_in[8];
    const float* mlw2   = (const float*)d_in[9];
    const float* mlb2   = (const float*)d_in[10];
    const float* mgamma = (const float*)d_in[11];
    const float* mbeta  = (const float*)d_in[12];
    const float* w1     = (const float*)d_in[13];
    const float* b1     = (const float*)d_in[14];
    const float* w2     = (const float*)d_in[15];
    const float* b2     = (const float*)d_in[16];
    const float* gw     = (const float*)d_in[17];
    const float* gb     = (const float*)d_in[18];
    const float* lw     = (const float*)d_in[19];
    const float* lb     = (const float*)d_in[20];
    const float* gamma  = (const float*)d_in[21];
    const float* beta   = (const float*)d_in[22];

    float* out  = (float*)d_out;                 // [B,64]
    float* mask = out + (size_t)NB * 64;         // [B,32]

    short* wfrag  = (short*)d_ws;                // 65536 frags (grn weights)
    short* mwfrag = wfrag + (size_t)65536 * 8;   // 24576 frags (mask big GEMM)
    short* swfrag = wfrag + (size_t)90112 * 8;   // 512 frags (mw2/mgw/mlw2)

    hipLaunchKernelGGL(prep_kernel, dim3(354), dim3(256), 0, stream,
                       w1, w2, gw, lw, mw1, mlw, mw2, mgw, mlw2, wfrag);
    hipLaunchKernelGGL(fused_kernel, dim3(NB / 16), dim3(256), 0, stream,
                       x, wfrag, mwfrag, swfrag,
                       mb1, mb2, mlb, mgb, mlb2, mgamma, mbeta,
                       b1, b2, gb, lb, gamma, beta,
                       mask, out);
}